// Round 4
// baseline (672.500 us; speedup 1.0000x reference)
//
#include <hip/hip_runtime.h>

#define MM 1024
#define NN 4096
#define DD 128
#define HH 32
#define LL 4096
#define PP 2048

typedef __attribute__((ext_vector_type(8))) short short8;
typedef __attribute__((ext_vector_type(4))) float f32x4;

__device__ __forceinline__ ushort f2bf(float f) {
  unsigned u = __builtin_bit_cast(unsigned, f);
  u += 0x7fffu + ((u >> 16) & 1u);
  return (ushort)(u >> 16);
}

__device__ __forceinline__ void gl_lds16(const void* g, void* l) {
  __builtin_amdgcn_global_load_lds(
      (const __attribute__((address_space(1))) void*)g,
      (__attribute__((address_space(3))) void*)l, 16, 0, 0);
}

// ---------------- fp32 -> bf16 convert (8 elts/thread) ----------------
__global__ __launch_bounds__(256) void convert_kernel(
    const float* __restrict__ src, ushort* __restrict__ dst, int n8) {
  int i = blockIdx.x * 256 + threadIdx.x;
  if (i >= n8) return;
  const float4* s = (const float4*)src + (size_t)i * 2;
  float4 a = s[0], b = s[1];
  union { ushort s[8]; uint4 v; } pk;
  pk.s[0] = f2bf(a.x); pk.s[1] = f2bf(a.y);
  pk.s[2] = f2bf(a.z); pk.s[3] = f2bf(a.w);
  pk.s[4] = f2bf(b.x); pk.s[5] = f2bf(b.y);
  pk.s[6] = f2bf(b.z); pk.s[7] = f2bf(b.w);
  ((uint4*)dst)[i] = pk.v;
}

// ------- transpose+convert W (3x fp32 [N,N] -> bf16 Wt[j][k] = W[k][j]) -------
__global__ __launch_bounds__(256) void transpose_w_kernel(
    const float* __restrict__ W0, const float* __restrict__ W1,
    const float* __restrict__ W2, ushort* __restrict__ Wt) {
  __shared__ __align__(16) ushort tile[64][72];  // 144B pitch (16B-aligned)
  int z = blockIdx.z;
  const float* W = (z == 0) ? W0 : ((z == 1) ? W1 : W2);
  ushort* out = Wt + (size_t)z * NN * NN;
  int r0 = blockIdx.x * 64, c0 = blockIdx.y * 64;
  int t = threadIdx.x;
#pragma unroll
  for (int i = 0; i < 4; ++i) {
    int c = i * 256 + t;
    int r = c >> 4, cc = (c & 15) * 4;
    float4 v = *(const float4*)(W + (size_t)(r0 + r) * NN + c0 + cc);
    tile[r][cc + 0] = f2bf(v.x);
    tile[r][cc + 1] = f2bf(v.y);
    tile[r][cc + 2] = f2bf(v.z);
    tile[r][cc + 3] = f2bf(v.w);
  }
  __syncthreads();
#pragma unroll
  for (int i = 0; i < 2; ++i) {
    int c = i * 256 + t;
    int j = c >> 3, kk = (c & 7) * 8;
    union { ushort s[8]; uint4 v; } pk;
#pragma unroll
    for (int u = 0; u < 8; ++u) pk.s[u] = tile[kk + u][j];
    *(uint4*)(out + (size_t)(c0 + j) * NN + r0 + kk) = pk.v;
  }
}

// --- build bf16 Vt[h][d][l] from fp32 cache_V (+ bf16 new v rows at P..P+M) ---
__global__ __launch_bounds__(256) void transpose_v_kernel(
    const float* __restrict__ cacheV, const ushort* __restrict__ v_new,
    ushort* __restrict__ Vt) {
  __shared__ __align__(16) ushort tile[64][72];
  int l0 = blockIdx.x * 64, d0 = blockIdx.y * 64, h = blockIdx.z;
  int t = threadIdx.x;
  bool isnew = (l0 >= PP && l0 < PP + MM);
  if (isnew) {
    const ushort* src = v_new + (size_t)(l0 - PP) * NN + h * DD + d0;
#pragma unroll
    for (int i = 0; i < 2; ++i) {
      int c = i * 256 + t;
      int r = c >> 3, cc = (c & 7) * 8;
      *(uint4*)&tile[r][cc] = *(const uint4*)(src + (size_t)r * NN + cc);
    }
  } else {
    const float* src = cacheV + ((size_t)h * LL + l0) * DD + d0;
#pragma unroll
    for (int i = 0; i < 4; ++i) {
      int c = i * 256 + t;
      int r = c >> 4, cc = (c & 15) * 4;
      float4 v = *(const float4*)(src + (size_t)r * DD + cc);
      tile[r][cc + 0] = f2bf(v.x);
      tile[r][cc + 1] = f2bf(v.y);
      tile[r][cc + 2] = f2bf(v.z);
      tile[r][cc + 3] = f2bf(v.w);
    }
  }
  __syncthreads();
#pragma unroll
  for (int i = 0; i < 2; ++i) {
    int c = i * 256 + t;
    int j = c >> 3, kk = (c & 7) * 8;
    union { ushort s[8]; uint4 v; } pk;
#pragma unroll
    for (int u = 0; u < 8; ++u) pk.s[u] = tile[kk + u][j];
    *(uint4*)(Vt + ((size_t)(h * DD + d0 + j)) * LL + l0 + kk) = pk.v;
  }
}

// ---------------- QKV GEMM: C[m][col] = sum_k Xb[m][k] * Wt[col][k] ----------------
// 128x128 tile, BK=64, global_load_lds(16B), XOR-swizzled LDS chunks.
__global__ __launch_bounds__(256) void qkv_gemm_kernel(
    const ushort* __restrict__ X, const ushort* __restrict__ Wt,
    ushort* __restrict__ q_ws, ushort* __restrict__ k_ws,
    ushort* __restrict__ v_ws) {
  __shared__ __align__(16) ushort Alds[128 * 64];
  __shared__ __align__(16) ushort Blds[128 * 64];
  int t = threadIdx.x;
  int lane = t & 63, quad = lane >> 4, l15 = lane & 15;
  int wv = t >> 6, wm = wv >> 1, wn = wv & 1;
  int m0 = blockIdx.x * 128;
  int wsel = blockIdx.y >> 5;
  int col0 = (blockIdx.y & 31) * 128;
  const ushort* Wsrc = Wt + (size_t)wsel * NN * NN + (size_t)col0 * NN;
  ushort* dst = (wsel == 0) ? q_ws : ((wsel == 1) ? k_ws : v_ws);

  int wuni = __builtin_amdgcn_readfirstlane(t & 192);  // wave base thread

  const ushort* aG[4];
  const ushort* bG[4];
  unsigned ldsb[4];
#pragma unroll
  for (int i = 0; i < 4; ++i) {
    int c = i * 256 + t;
    int row = c >> 3, g = (c & 7) ^ (row & 7);
    aG[i] = X + (size_t)(m0 + row) * NN + g * 8;
    bG[i] = Wsrc + (size_t)row * NN + g * 8;
    ldsb[i] = (unsigned)(i * 256 + wuni) * 16u;
  }
  unsigned aAddr[4][2], bAddr[4][2];
#pragma unroll
  for (int mb = 0; mb < 4; ++mb)
#pragma unroll
    for (int s = 0; s < 2; ++s) {
      int row = wm * 64 + mb * 16 + l15;
      int g = s * 4 + quad;
      aAddr[mb][s] = (unsigned)(row * 128 + ((g ^ (row & 7)) * 16));
    }
#pragma unroll
  for (int nb = 0; nb < 4; ++nb)
#pragma unroll
    for (int s = 0; s < 2; ++s) {
      int row = wn * 64 + nb * 16 + l15;
      int g = s * 4 + quad;
      bAddr[nb][s] = (unsigned)(row * 128 + ((g ^ (row & 7)) * 16));
    }

  f32x4 acc[4][4];
#pragma unroll
  for (int mb = 0; mb < 4; ++mb)
#pragma unroll
    for (int nb = 0; nb < 4; ++nb) acc[mb][nb] = (f32x4){0.f, 0.f, 0.f, 0.f};

  for (int kt = 0; kt < 64; ++kt) {
#pragma unroll
    for (int i = 0; i < 4; ++i) gl_lds16(aG[i], (char*)Alds + ldsb[i]);
#pragma unroll
    for (int i = 0; i < 4; ++i) gl_lds16(bG[i], (char*)Blds + ldsb[i]);
#pragma unroll
    for (int i = 0; i < 4; ++i) { aG[i] += 64; bG[i] += 64; }
    __syncthreads();  // drains vmcnt -> tiles visible
#pragma unroll
    for (int s = 0; s < 2; ++s) {
      short8 af[4], bf[4];
#pragma unroll
      for (int mb = 0; mb < 4; ++mb)
        af[mb] = *(const short8*)((const char*)Alds + aAddr[mb][s]);
#pragma unroll
      for (int nb = 0; nb < 4; ++nb)
        bf[nb] = *(const short8*)((const char*)Blds + bAddr[nb][s]);
#pragma unroll
      for (int mb = 0; mb < 4; ++mb)
#pragma unroll
        for (int nb = 0; nb < 4; ++nb)
          acc[mb][nb] = __builtin_amdgcn_mfma_f32_16x16x32_bf16(
              af[mb], bf[nb], acc[mb][nb], 0, 0, 0);
    }
    __syncthreads();  // done reading before next stage overwrites
  }

#pragma unroll
  for (int mb = 0; mb < 4; ++mb)
#pragma unroll
    for (int nb = 0; nb < 4; ++nb)
#pragma unroll
      for (int r = 0; r < 4; ++r) {
        int row = m0 + wm * 64 + mb * 16 + quad * 4 + r;
        int col = col0 + wn * 64 + nb * 16 + l15;
        dst[(size_t)row * NN + col] = f2bf(acc[mb][nb][r]);
      }
}

// ---------------- fused attention: one head x 32 queries per block ----------------
// Latency-bound fix: 4 blocks/CU occupancy, 1 barrier/iter, packed P writes.
//   - Swapped QK^T: S = mfma(K, Q) -> lane holds S[l=wv16+quad4+r][m=mb*16+l15],
//     i.e. 4 CONSECUTIVE l at fixed m -> P write = 2 cvt_pk + 1 ds_write_b64/mb.
//   - P double-buffered (parity lt&1) -> single s_barrier per iteration.
//   - K direct global->reg double-buffered (prefetch 1 tile ahead, counted vmcnt);
//     V single reg buffer loaded at iter top (consumed after the barrier).
//   - den: 1 scalar/mb per lane, reduced in epilogue.
__global__ __launch_bounds__(256, 4) void attn_kernel(
    const ushort* __restrict__ q_ws, const ushort* __restrict__ k_ws,
    const ushort* __restrict__ Kb, const ushort* __restrict__ Vt,
    float* __restrict__ out) {
  // LDS: Plds[2]: 32m x 72 ushorts, pitch 144B @0 / @4608 (9216B total)
  //      Olds float[32][136] @0 (17408B, epilogue reuse)
  //      denlds float[4][32] @17408 (512B). Total 17920B -> LDS not limiting.
  __shared__ __align__(16) char smem[17920];
  float* denlds = (float*)(smem + 17408);
  float* Olds = (float*)smem;

  int t = threadIdx.x;
  int lane = t & 63, quad = lane >> 4, l15 = lane & 15;
  int wv = t >> 6;
  int quad8 = quad * 8, quad4 = quad * 4, quad16 = quad * 16;
  int wv16 = wv * 16;
  int wv16l15 = wv16 + l15;
  // XCD swizzle: 1024 blocks, 128/XCD = 4 heads -> K/V stay L2-hot per XCD.
  int flat = (int)(blockIdx.y * 32 + blockIdx.x);
  int swz = ((flat & 7) << 7) | (flat >> 3);
  int m0 = (swz & 31) * 32;
  int h = swz >> 5;

  // Q frags (B-operand): rows m = m0 + mb*16 + l15, k-chunk = ds*32 + quad8
  short8 qf[2][4];
#pragma unroll
  for (int mb = 0; mb < 2; ++mb) {
    const ushort* qr =
        q_ws + (size_t)(m0 + mb * 16 + l15) * NN + h * DD + quad8;
#pragma unroll
    for (int ds = 0; ds < 4; ++ds) qf[mb][ds] = *(const short8*)(qr + ds * 32);
  }

  // K per-lane base pointers (row l = wv16 + l15 within each 64-l tile)
  const ushort* kbK = Kb + ((size_t)h * LL + wv16l15) * DD;
  const ushort* kbW = k_ws + (size_t)wv16l15 * NN + h * DD;
  // V row bases: d = wv*32 + l15 (db=0) / +16 (db=1)
  const ushort* vrow = Vt + ((size_t)(h * DD + wv * 32 + l15)) * LL;
  const ushort* vrow16 = vrow + (size_t)16 * LL;

  f32x4 Oacc[2][2];
#pragma unroll
  for (int db = 0; db < 2; ++db)
#pragma unroll
    for (int mb = 0; mb < 2; ++mb) Oacc[db][mb] = (f32x4){0.f, 0.f, 0.f, 0.f};
  float denp0 = 0.f, denp1 = 0.f;

  short8 kra[4], krb[4], vc[2][2];

  // prologue: K tile 0 (l0 = 0 -> cache region)
  kra[0] = *(const short8*)(kbK + quad8);
  kra[1] = *(const short8*)(kbK + 32 + quad8);
  kra[2] = *(const short8*)(kbK + 64 + quad8);
  kra[3] = *(const short8*)(kbK + 96 + quad8);

#define ATTN_STEP(LT, KC, KN, PF)                                              \
  do {                                                                         \
    const int l0c = (LT) << 6;                                                 \
    const unsigned pb = (((LT) & 1) ? 4608u : 0u);                             \
    /* V for current tile (consumed after the barrier; ~QK+exp of cover) */    \
    vc[0][0] = *(const short8*)(vrow + l0c + quad8);                           \
    vc[0][1] = *(const short8*)(vrow + l0c + 32 + quad8);                      \
    vc[1][0] = *(const short8*)(vrow16 + l0c + quad8);                         \
    vc[1][1] = *(const short8*)(vrow16 + l0c + 32 + quad8);                    \
    if (PF) { /* K prefetch tile LT+1 (stays in flight across barrier) */      \
      const int l0n = ((LT) + 1) << 6;                                         \
      const ushort* kp = (l0n >= PP && l0n < PP + MM)                          \
                             ? kbW + (size_t)(l0n - PP) * NN                   \
                             : kbK + (size_t)l0n * DD;                         \
      KN[0] = *(const short8*)(kp + quad8);                                    \
      KN[1] = *(const short8*)(kp + 32 + quad8);                               \
      KN[2] = *(const short8*)(kp + 64 + quad8);                               \
      KN[3] = *(const short8*)(kp + 96 + quad8);                               \
    }                                                                          \
    /* QK^T swapped: A=K rows l, B=Q rows m; lane: l=wv16+quad4+r, m=mb16+l15*/\
    f32x4 s0 = (f32x4){0.f, 0.f, 0.f, 0.f};                                    \
    f32x4 s1 = (f32x4){0.f, 0.f, 0.f, 0.f};                                    \
    __builtin_amdgcn_s_setprio(1);                                             \
    s0 = __builtin_amdgcn_mfma_f32_16x16x32_bf16(KC[0], qf[0][0], s0, 0, 0, 0);\
    s1 = __builtin_amdgcn_mfma_f32_16x16x32_bf16(KC[0], qf[1][0], s1, 0, 0, 0);\
    s0 = __builtin_amdgcn_mfma_f32_16x16x32_bf16(KC[1], qf[0][1], s0, 0, 0, 0);\
    s1 = __builtin_amdgcn_mfma_f32_16x16x32_bf16(KC[1], qf[1][1], s1, 0, 0, 0);\
    s0 = __builtin_amdgcn_mfma_f32_16x16x32_bf16(KC[2], qf[0][2], s0, 0, 0, 0);\
    s1 = __builtin_amdgcn_mfma_f32_16x16x32_bf16(KC[2], qf[1][2], s1, 0, 0, 0);\
    s0 = __builtin_amdgcn_mfma_f32_16x16x32_bf16(KC[3], qf[0][3], s0, 0, 0, 0);\
    s1 = __builtin_amdgcn_mfma_f32_16x16x32_bf16(KC[3], qf[1][3], s1, 0, 0, 0);\
    __builtin_amdgcn_s_setprio(0);                                             \
    { /* exp + pack 4 consecutive-l bf16 -> one b64 write per mb */            \
      float e0 = __expf(s0[0]), e1 = __expf(s0[1]);                            \
      float e2 = __expf(s0[2]), e3 = __expf(s0[3]);                            \
      denp0 += (e0 + e1) + (e2 + e3);                                          \
      unsigned w0, w1;                                                         \
      asm("v_cvt_pk_bf16_f32 %0, %1, %2" : "=v"(w0) : "v"(e0), "v"(e1));       \
      asm("v_cvt_pk_bf16_f32 %0, %1, %2" : "=v"(w1) : "v"(e2), "v"(e3));       \
      uint2 pw; pw.x = w0; pw.y = w1;                                          \
      *(uint2*)(smem + pb + (unsigned)l15 * 144u + (unsigned)(wv16 * 2) +      \
                (unsigned)quad8) = pw;                                         \
      float f0 = __expf(s1[0]), f1 = __expf(s1[1]);                            \
      float f2 = __expf(s1[2]), f3 = __expf(s1[3]);                            \
      denp1 += (f0 + f1) + (f2 + f3);                                          \
      unsigned w2, w3;                                                         \
      asm("v_cvt_pk_bf16_f32 %0, %1, %2" : "=v"(w2) : "v"(f0), "v"(f1));       \
      asm("v_cvt_pk_bf16_f32 %0, %1, %2" : "=v"(w3) : "v"(f2), "v"(f3));       \
      uint2 pw2; pw2.x = w2; pw2.y = w3;                                       \
      *(uint2*)(smem + pb + (unsigned)(16 + l15) * 144u +                      \
                (unsigned)(wv16 * 2) + (unsigned)quad8) = pw2;                 \
    }                                                                          \
    asm volatile("s_waitcnt lgkmcnt(0)" ::: "memory");                         \
    __builtin_amdgcn_s_barrier(); /* P ready; K prefetch stays in flight */    \
    asm volatile("" ::: "memory");                                             \
    /* PV: O^T[d][m]; A = V^T frags (regs), B = P frags (LDS) */               \
    __builtin_amdgcn_s_setprio(1);                                             \
    _Pragma("unroll") for (int mb = 0; mb < 2; ++mb) {                         \
      const char* pr = smem + pb + (unsigned)(mb * 16 + l15) * 144u;           \
      short8 p0 = *(const short8*)(pr + quad16);                               \
      short8 p1 = *(const short8*)(pr + 64 + quad16);                          \
      Oacc[0][mb] = __builtin_amdgcn_mfma_f32_16x16x32_bf16(                   \
          vc[0][0], p0, Oacc[0][mb], 0, 0, 0);                                 \
      Oacc[0][mb] = __builtin_amdgcn_mfma_f32_16x16x32_bf16(                   \
          vc[0][1], p1, Oacc[0][mb], 0, 0, 0);                                 \
      Oacc[1][mb] = __builtin_amdgcn_mfma_f32_16x16x32_bf16(                   \
          vc[1][0], p0, Oacc[1][mb], 0, 0, 0);                                 \
      Oacc[1][mb] = __builtin_amdgcn_mfma_f32_16x16x32_bf16(                   \
          vc[1][1], p1, Oacc[1][mb], 0, 0, 0);                                 \
    }                                                                          \
    __builtin_amdgcn_s_setprio(0);                                             \
  } while (0)

  for (int i = 0; i < 31; ++i) {
    ATTN_STEP(2 * i, kra, krb, 1);
    ATTN_STEP(2 * i + 1, krb, kra, 1);
  }
  ATTN_STEP(62, kra, krb, 1);
  ATTN_STEP(63, krb, kra, 0);
#undef ATTN_STEP

  // ---- epilogue: den reduce (sum over l) ----
  // lane holds partial for m = mb*16 + l15 over its l-slices; reduce over
  // quad bits (lane^16, lane^32), then across the 4 waves via LDS.
  {
    float v0 = denp0, v1 = denp1;
    v0 += __shfl_xor(v0, 16);
    v0 += __shfl_xor(v0, 32);
    v1 += __shfl_xor(v1, 16);
    v1 += __shfl_xor(v1, 32);
    if (quad == 0) {
      denlds[wv * 32 + l15] = v0;
      denlds[wv * 32 + 16 + l15] = v1;
    }
  }
  __syncthreads();  // den ready; also guards Plds reads before Olds overwrite

  // divide + transpose O^T -> O via LDS (fp32, pitch 136)
#pragma unroll
  for (int mb = 0; mb < 2; ++mb) {
    int m = mb * 16 + l15;
    float den =
        denlds[m] + denlds[32 + m] + denlds[64 + m] + denlds[96 + m];
    float inv = 1.0f / den;
#pragma unroll
    for (int db = 0; db < 2; ++db)
#pragma unroll
      for (int r = 0; r < 4; ++r) {
        int d = wv * 32 + db * 16 + quad4 + r;
        Olds[m * 136 + d] = Oacc[db][mb][r] * inv;
      }
  }
  __syncthreads();
  {
    int m = t >> 3, c0 = (t & 7) * 16;
    float* orow = out + (size_t)(m0 + m) * NN + h * DD + c0;
#pragma unroll
    for (int j = 0; j < 16; j += 4) {
      float4 v;
      v.x = Olds[m * 136 + c0 + j + 0];
      v.y = Olds[m * 136 + c0 + j + 1];
      v.z = Olds[m * 136 + c0 + j + 2];
      v.w = Olds[m * 136 + c0 + j + 3];
      *(float4*)(orow + j) = v;
    }
  }
}

extern "C" void kernel_launch(void* const* d_in, const int* in_sizes, int n_in,
                              void* d_out, int out_size, void* d_ws,
                              size_t ws_size, hipStream_t stream) {
  const float* X = (const float*)d_in[0];
  const float* Wq = (const float*)d_in[1];
  const float* Wk = (const float*)d_in[2];
  const float* Wv = (const float*)d_in[3];
  const float* cK = (const float*)d_in[4];
  const float* cV = (const float*)d_in[5];
  float* out = (float*)d_out;
  char* wsb = (char*)d_ws;

  // ws layout (bytes) — Kb/Vt alias Wt (dead after GEMM). Total 128 MiB.
  ushort* Wt = (ushort*)wsb;                         // 100,663,296
  ushort* Kb = (ushort*)wsb;                         // 33,554,432 (alias)
  ushort* Vt = (ushort*)(wsb + 33554432);            // 33,554,432 (alias)
  ushort* Xb = (ushort*)(wsb + 100663296);           // 8,388,608
  ushort* q_ws = (ushort*)(wsb + 109051904);         // 8,388,608
  ushort* k_ws = (ushort*)(wsb + 117440512);         // 8,388,608
  ushort* v_ws = (ushort*)(wsb + 125829120);         // 8,388,608

  convert_kernel<<<2048, 256, 0, stream>>>(X, Xb, MM * NN / 8);
  transpose_w_kernel<<<dim3(64, 64, 3), 256, 0, stream>>>(Wq, Wk, Wv, Wt);
  qkv_gemm_kernel<<<dim3(8, 96), 256, 0, stream>>>(Xb, Wt, q_ws, k_ws, v_ws);
  convert_kernel<<<8192, 256, 0, stream>>>(cK, Kb, HH * LL * DD / 8);
  transpose_v_kernel<<<dim3(64, 2, 32), 256, 0, stream>>>(cV, v_ws, Vt);
  attn_kernel<<<dim3(32, 32), 256, 0, stream>>>(q_ws, k_ws, Kb, Vt, out);
}